// Round 1
// baseline (399.535 us; speedup 1.0000x reference)
//
#include <hip/hip_runtime.h>
#include <stdint.h>

// ---------------- problem constants ----------------
#define N_NODES 50000
#define N_EDGES 800000
#define IN_CH   256
#define HC      256      // HEADS * CPH
#define HEADS   8
#define SLOPE   0.2f
#define MPAD    50048    // 391 * 128 (GEMM row padding)
#define NB_SCAN 196      // ceil(50000/256)
#define MAXE    256      // max in-degree capacity (Poisson(16): P(deg>100) ~ 0)

typedef __attribute__((ext_vector_type(8))) short bf16x8;
typedef __attribute__((ext_vector_type(4))) float f32x4;
typedef unsigned short u16;
typedef unsigned int   u32;
typedef unsigned long long u64;

static __device__ __forceinline__ float bf2f(u16 u) {
    return __uint_as_float(((u32)u) << 16);
}
static __device__ __forceinline__ u16 f2bf(float f) {
    u32 b = __float_as_uint(f);
    b += 0x7fffu + ((b >> 16) & 1u);   // RNE (finite values)
    return (u16)(b >> 16);
}

// ---------------- x -> bf16 (rows >= N zero-padded) ----------------
__global__ void k_conv_x(const float* __restrict__ x, u16* __restrict__ xb) {
    int idx  = blockIdx.x * 256 + threadIdx.x;   // 4 elements / thread
    int base = idx * 4;
    if (base >= MPAD * IN_CH) return;
    int row = base >> 8;
    float4 v = make_float4(0.f, 0.f, 0.f, 0.f);
    if (row < N_NODES) v = *(const float4*)(x + base);
    u64 pk = (u64)f2bf(v.x) | ((u64)f2bf(v.y) << 16) |
             ((u64)f2bf(v.z) << 32) | ((u64)f2bf(v.w) << 48);
    *(u64*)(xb + base) = pk;
}

// ---------------- W (K,HC) -> Wt (HC,K) bf16 ----------------
__global__ void k_conv_w(const float* __restrict__ W, u16* __restrict__ Wt) {
    int hc = blockIdx.x, k = threadIdx.x;
    Wt[hc * 256 + k] = f2bf(W[k * 256 + hc]);
}

// ---------------- bf16 MFMA GEMM: xh = x @ W  (MPADx256 * 256x256) ----------------
__launch_bounds__(256)
__global__ void k_gemm(const u16* __restrict__ A, const u16* __restrict__ B,
                       u16* __restrict__ C) {
    __shared__ u16 As[128 * 64];   // [row][k] 16KB
    __shared__ u16 Bs[128 * 64];   // [col][k] 16KB (B = Wt, row-major = W col-major)
    const int tid  = threadIdx.x;
    const int lane = tid & 63;
    const int w    = tid >> 6;          // 4 waves
    const int wm   = w >> 1, wn = w & 1; // 2x2 wave grid of 64x64
    const int bm = blockIdx.x, bn = blockIdx.y;
    const int arow0 = bm * 128;
    const int brow0 = bn * 128;

    f32x4 acc[4][4];
#pragma unroll
    for (int m = 0; m < 4; m++)
#pragma unroll
        for (int n = 0; n < 4; n++) acc[m][n] = (f32x4){0.f, 0.f, 0.f, 0.f};

    for (int kt = 0; kt < 4; ++kt) {
        // stage A+B tiles (reg-staged, 16B per thread per tile-quarter)
#pragma unroll
        for (int i = 0; i < 4; i++) {
            int chunk = tid + i * 256;          // 0..1023
            int r = chunk >> 3, ch = chunk & 7; // row, 16B chunk in row
            bf16x8 va = *(const bf16x8*)(A + (arow0 + r) * 256 + kt * 64 + ch * 8);
            *(bf16x8*)(As + r * 64 + ch * 8) = va;
            bf16x8 vb = *(const bf16x8*)(B + (brow0 + r) * 256 + kt * 64 + ch * 8);
            *(bf16x8*)(Bs + r * 64 + ch * 8) = vb;
        }
        __syncthreads();
#pragma unroll
        for (int kk = 0; kk < 2; kk++) {
            bf16x8 af[4], bf[4];
#pragma unroll
            for (int m = 0; m < 4; m++)
                af[m] = *(const bf16x8*)(As + (wm * 64 + m * 16 + (lane & 15)) * 64 +
                                         kk * 32 + (lane >> 4) * 8);
#pragma unroll
            for (int n = 0; n < 4; n++)
                bf[n] = *(const bf16x8*)(Bs + (wn * 64 + n * 16 + (lane & 15)) * 64 +
                                         kk * 32 + (lane >> 4) * 8);
#pragma unroll
            for (int m = 0; m < 4; m++)
#pragma unroll
                for (int n = 0; n < 4; n++)
                    acc[m][n] = __builtin_amdgcn_mfma_f32_16x16x32_bf16(
                        af[m], bf[n], acc[m][n], 0, 0, 0);
        }
        __syncthreads();
    }
    // epilogue: C/D layout col=lane&15, row=(lane>>4)*4+j
#pragma unroll
    for (int m = 0; m < 4; m++) {
        int r0 = wm * 64 + m * 16 + (lane >> 4) * 4;
#pragma unroll
        for (int n = 0; n < 4; n++) {
            int col = bn * 128 + wn * 64 + n * 16 + (lane & 15);
#pragma unroll
            for (int j = 0; j < 4; j++)
                C[(arow0 + r0 + j) * 256 + col] = f2bf(acc[m][n][j]);
        }
    }
}

// ---------------- per-node attention logits a_src/a_dst ----------------
__global__ void k_node_att(const u16* __restrict__ xh, const float* __restrict__ att_s,
                           const float* __restrict__ att_d, float* __restrict__ a_src,
                           float* __restrict__ a_dst) {
    int i = blockIdx.x, t = threadIdx.x;
    float v = bf2f(xh[i * 256 + t]);
    float s = v * att_s[t], d = v * att_d[t];
#pragma unroll
    for (int m = 16; m >= 1; m >>= 1) {
        s += __shfl_xor(s, m);
        d += __shfl_xor(d, m);
    }
    if ((t & 31) == 0) {
        a_src[i * 8 + (t >> 5)] = s;
        a_dst[i * 8 + (t >> 5)] = d;
    }
}

// ---------------- CSR build: histogram / scan / scatter ----------------
__global__ void k_hist(const int* __restrict__ ei, int* __restrict__ deg) {
    int e = blockIdx.x * 256 + threadIdx.x;
    if (e >= N_EDGES) return;
    atomicAdd(&deg[ei[N_EDGES + e]], 1);
}

__global__ void k_scan1(const int* __restrict__ deg, int* __restrict__ incl,
                        int* __restrict__ bsum) {
    __shared__ int s[256];
    int t = threadIdx.x, idx = blockIdx.x * 256 + t;
    int v = (idx < N_NODES) ? deg[idx] + 1 : 0;   // +1 = self loop slot
    s[t] = v;
    __syncthreads();
    for (int off = 1; off < 256; off <<= 1) {
        int u = (t >= off) ? s[t - off] : 0;
        __syncthreads();
        s[t] += u;
        __syncthreads();
    }
    incl[idx] = s[t];
    if (t == 255) bsum[blockIdx.x] = s[255];
}

__global__ void k_scan2(const int* __restrict__ bsum, int* __restrict__ boff) {
    __shared__ int s[256];
    int t = threadIdx.x;
    int v = (t < NB_SCAN) ? bsum[t] : 0;
    s[t] = v;
    __syncthreads();
    for (int off = 1; off < 256; off <<= 1) {
        int u = (t >= off) ? s[t - off] : 0;
        __syncthreads();
        s[t] += u;
        __syncthreads();
    }
    boff[t] = s[t] - v;   // exclusive
}

__global__ void k_scan3(const int* __restrict__ deg, const int* __restrict__ incl,
                        const int* __restrict__ boff, int* __restrict__ row_start,
                        int* __restrict__ cursor) {
    int idx = blockIdx.x * 256 + threadIdx.x;
    if (idx < N_NODES) {
        int ex = incl[idx] - (deg[idx] + 1) + boff[idx >> 8];
        row_start[idx] = ex;
        cursor[idx]    = ex;
    }
    if (idx == 0) row_start[N_NODES] = N_EDGES + N_NODES;
}

__global__ void k_scatter(const int* __restrict__ ei, int* __restrict__ cursor,
                          int2* __restrict__ sorted) {
    int e = blockIdx.x * 256 + threadIdx.x;
    if (e >= N_EDGES) return;
    int s = ei[e], d = ei[N_EDGES + e];
    int pos = atomicAdd(&cursor[d], 1);
    sorted[pos] = make_int2(s, e);
}

// ---------------- per-node softmax + aggregation ----------------
__launch_bounds__(256)
__global__ void k_node(const u16* __restrict__ xh, const int2* __restrict__ sorted,
                       const int* __restrict__ row_start, const float* __restrict__ a_src,
                       const float* __restrict__ a_dstg, const float* __restrict__ x,
                       const float* __restrict__ bias, float* __restrict__ out,
                       float* __restrict__ alpha) {
    __shared__ float eL[MAXE * 8];
    __shared__ int   sL[MAXE];
    __shared__ int   idL[MAXE];
    __shared__ float adst[8], mh[8], dh[8];
    const int i = blockIdx.x, t = threadIdx.x;
    const int start = row_start[i];
    int cnt = row_start[i + 1] - start;   // includes self slot
    if (cnt > MAXE) cnt = MAXE;           // statistically impossible; OOB guard
    const int degE = cnt - 1;

    if (t < 8) adst[t] = a_dstg[i * 8 + t];
    for (int k = t; k < cnt; k += 256) {
        if (k < degE) {
            int2 pr = sorted[start + k];
            sL[k] = pr.x;
            idL[k] = pr.y;
        } else {
            sL[k] = i;
            idL[k] = N_EDGES + i;
        }
    }
    __syncthreads();

    const int tot = cnt * 8;
    for (int idx = t; idx < tot; idx += 256) {
        int k = idx >> 3, h = idx & 7;
        float s = a_src[sL[k] * 8 + h] + adst[h];
        eL[k * 8 + h] = (s >= 0.f) ? s : SLOPE * s;
    }
    __syncthreads();

    // per-head max (head = t>>5, 32 lanes per head)
    {
        int h = t >> 5, c = t & 31;
        float pm = -1e30f;
        for (int k = c; k < cnt; k += 32) pm = fmaxf(pm, eL[k * 8 + h]);
#pragma unroll
        for (int m = 16; m >= 1; m >>= 1) pm = fmaxf(pm, __shfl_xor(pm, m));
        if (c == 0) mh[h] = pm;
    }
    __syncthreads();
    // exp + per-head sum
    {
        int h = t >> 5, c = t & 31;
        float m = mh[h], ps = 0.f;
        for (int k = c; k < cnt; k += 32) {
            float ex = __expf(eL[k * 8 + h] - m);
            eL[k * 8 + h] = ex;
            ps += ex;
        }
#pragma unroll
        for (int mm = 16; mm >= 1; mm >>= 1) ps += __shfl_xor(ps, mm);
        if (c == 0) dh[h] = ps;
    }
    __syncthreads();
    // alpha = ex/denom; write to global at original edge id
    for (int idx = t; idx < tot; idx += 256) {
        int k = idx >> 3, h = idx & 7;
        float a = eL[k * 8 + h] / (dh[h] + 1e-16f);
        eL[k * 8 + h] = a;
        alpha[(long)idL[k] * 8 + h] = a;
    }
    __syncthreads();
    // aggregate: out[i][c] = sum_k alpha[k][c>>5] * xh[src_k][c] + bias + x
    {
        int c = t, h = c >> 5;
        float acc = 0.f;
        for (int k = 0; k < cnt; k++)
            acc += eL[k * 8 + h] * bf2f(xh[(long)sL[k] * 256 + c]);
        out[(long)i * 256 + c] = acc + bias[c] + x[(long)i * 256 + c];
    }
}

extern "C" void kernel_launch(void* const* d_in, const int* in_sizes, int n_in,
                              void* d_out, int out_size, void* d_ws, size_t ws_size,
                              hipStream_t stream) {
    const float* x     = (const float*)d_in[0];
    const int*   ei    = (const int*)d_in[1];    // (2,E) int32
    const float* W     = (const float*)d_in[2];
    const float* att_s = (const float*)d_in[3];
    const float* att_d = (const float*)d_in[4];
    const float* bias  = (const float*)d_in[5];
    float* out   = (float*)d_out;
    float* alpha = out + (size_t)N_NODES * HC;

    char* p = (char*)d_ws;
    u16* xb = (u16*)p;        p += (size_t)MPAD * 256 * 2;
    u16* xh = (u16*)p;        p += (size_t)MPAD * 256 * 2;
    u16* Wt = (u16*)p;        p += 256 * 256 * 2;
    float* a_src = (float*)p; p += (size_t)N_NODES * 8 * 4;
    float* a_dst = (float*)p; p += (size_t)N_NODES * 8 * 4;
    int* deg  = (int*)p;      p += (size_t)N_NODES * 4;
    int* incl = (int*)p;      p += (size_t)NB_SCAN * 256 * 4;
    int* bsum = (int*)p;      p += 256 * 4;
    int* boff = (int*)p;      p += 256 * 4;
    int* row_start = (int*)p; p += ((size_t)(N_NODES + 1) * 4 + 15) / 16 * 16;
    int* cursor = (int*)p;    p += (size_t)N_NODES * 4;
    int2* sorted = (int2*)p;  p += (size_t)N_EDGES * 8;

    hipMemsetAsync(deg, 0, (size_t)N_NODES * 4, stream);
    k_conv_x<<<MPAD * 256 / 4 / 256, 256, 0, stream>>>(x, xb);
    k_conv_w<<<256, 256, 0, stream>>>(W, Wt);
    dim3 gg(MPAD / 128, 2);
    k_gemm<<<gg, 256, 0, stream>>>(xb, Wt, xh);
    k_node_att<<<N_NODES, 256, 0, stream>>>(xh, att_s, att_d, a_src, a_dst);
    k_hist<<<(N_EDGES + 255) / 256, 256, 0, stream>>>(ei, deg);
    k_scan1<<<NB_SCAN, 256, 0, stream>>>(deg, incl, bsum);
    k_scan2<<<1, 256, 0, stream>>>(bsum, boff);
    k_scan3<<<NB_SCAN, 256, 0, stream>>>(deg, incl, boff, row_start, cursor);
    k_scatter<<<(N_EDGES + 255) / 256, 256, 0, stream>>>(ei, cursor, sorted);
    k_node<<<N_NODES, 256, 0, stream>>>(xh, sorted, row_start, a_src, a_dst, x, bias,
                                        out, alpha);
}

// Round 3
// 336.074 us; speedup vs baseline: 1.1888x; 1.1888x over previous
//
#include <hip/hip_runtime.h>
#include <stdint.h>

// ---------------- problem constants ----------------
#define N_NODES 50000
#define N_EDGES 800000
#define IN_CH   256
#define HC      256      // HEADS * CPH
#define HEADS   8
#define SLOPE   0.2f
#define MPAD    50048    // 391 * 128 (GEMM row padding)
#define NB_SCAN 196      // ceil(50000/256)
#define MAXE    256      // max in-degree capacity (Poisson(16): P(deg>100) ~ 0)
#define EP      260      // eL row stride (bank-conflict-free: 260%32=4)

typedef __attribute__((ext_vector_type(8))) short bf16x8;
typedef __attribute__((ext_vector_type(4))) float f32x4;
typedef unsigned short u16;
typedef unsigned int   u32;
typedef unsigned long long u64;

static __device__ __forceinline__ float bf2f(u16 u) {
    return __uint_as_float(((u32)u) << 16);
}
static __device__ __forceinline__ u16 f2bf(float f) {
    u32 b = __float_as_uint(f);
    b += 0x7fffu + ((b >> 16) & 1u);   // RNE (finite values)
    return (u16)(b >> 16);
}

// async global->LDS, 16B per lane. LDS dest = wave-uniform base + lane*16.
// generic->AS cast via uintptr (CK idiom; LDS aperture low 32 bits == ds offset)
#define ASYNC16(g, l) __builtin_amdgcn_global_load_lds(                      \
    (const __attribute__((address_space(1))) u32*)(uintptr_t)(g),            \
    (__attribute__((address_space(3))) u32*)(uintptr_t)(l), 16, 0, 0)

// ---------------- x -> bf16 (rows >= N zero-padded), 8 elem/thread ----------------
__global__ void k_conv_x(const float* __restrict__ x, u16* __restrict__ xb) {
    size_t idx  = (size_t)blockIdx.x * 256 + threadIdx.x;
    size_t base = idx * 8;
    int row = (int)(base >> 8);
    float4 v0 = make_float4(0.f,0.f,0.f,0.f), v1 = v0;
    if (row < N_NODES) {
        v0 = *(const float4*)(x + base);
        v1 = *(const float4*)(x + base + 4);
    }
    u64 lo = (u64)f2bf(v0.x) | ((u64)f2bf(v0.y) << 16) |
             ((u64)f2bf(v0.z) << 32) | ((u64)f2bf(v0.w) << 48);
    u64 hi = (u64)f2bf(v1.x) | ((u64)f2bf(v1.y) << 16) |
             ((u64)f2bf(v1.z) << 32) | ((u64)f2bf(v1.w) << 48);
    *(u64*)(xb + base)     = lo;
    *(u64*)(xb + base + 4) = hi;
}

// ---------------- W (K,HC) -> Wt (HC,K) bf16 ----------------
__global__ void k_conv_w(const float* __restrict__ W, u16* __restrict__ Wt) {
    int hc = blockIdx.x, k = threadIdx.x;
    Wt[hc * 256 + k] = f2bf(W[k * 256 + hc]);
}

// ---------------- bf16 MFMA GEMM: xh = x @ W  (MPADx256 * 256x256) ----------------
// global_load_lds staging (linear LDS dest, XOR-swizzled global source),
// double-buffered; fragment ds_read uses the matching XOR -> ~2-way conflicts.
__device__ __forceinline__ void stage_tile(const u16* __restrict__ A,
                                           const u16* __restrict__ B,
                                           u16* as, u16* bs, int arow0, int brow0,
                                           int kt, int w, int rr, int ch) {
    int sch = ch ^ (rr & 7);   // source chunk swizzle (involution)
#pragma unroll
    for (int ii = 0; ii < 4; ii++) {
        int rq = w * 32 + ii * 8;   // 8-row group staged per issue (1KB)
        ASYNC16(A + (size_t)(arow0 + rq + rr) * 256 + kt * 64 + sch * 8, as + rq * 64);
        ASYNC16(B + (size_t)(brow0 + rq + rr) * 256 + kt * 64 + sch * 8, bs + rq * 64);
    }
}

__launch_bounds__(256)
__global__ void k_gemm(const u16* __restrict__ A, const u16* __restrict__ B,
                       u16* __restrict__ C) {
    __shared__ u16 As[2][128 * 64];   // [buf][row][64]
    __shared__ u16 Bs[2][128 * 64];
    const int tid  = threadIdx.x;
    const int lane = tid & 63;
    const int w    = tid >> 6;
    const int wm   = w >> 1, wn = w & 1;
    const int arow0 = blockIdx.x * 128;
    const int brow0 = blockIdx.y * 128;
    const int rr = lane >> 3, ch = lane & 7;

    f32x4 acc[4][4];
#pragma unroll
    for (int m = 0; m < 4; m++)
#pragma unroll
        for (int n = 0; n < 4; n++) acc[m][n] = (f32x4){0.f, 0.f, 0.f, 0.f};

    stage_tile(A, B, As[0], Bs[0], arow0, brow0, 0, w, rr, ch);
    __syncthreads();

    for (int kt = 0; kt < 4; ++kt) {
        int cur = kt & 1;
        if (kt < 3)
            stage_tile(A, B, As[cur ^ 1], Bs[cur ^ 1], arow0, brow0, kt + 1, w, rr, ch);
        const u16* as = As[cur];
        const u16* bs = Bs[cur];
#pragma unroll
        for (int kk = 0; kk < 2; kk++) {
            bf16x8 af[4], bv[4];
#pragma unroll
            for (int m = 0; m < 4; m++) {
                int row = wm * 64 + m * 16 + (lane & 15);
                int c   = (kk * 4 + (lane >> 4)) ^ (lane & 7);   // row&7 == lane&7
                af[m] = *(const bf16x8*)(as + row * 64 + c * 8);
            }
#pragma unroll
            for (int n = 0; n < 4; n++) {
                int row = wn * 64 + n * 16 + (lane & 15);
                int c   = (kk * 4 + (lane >> 4)) ^ (lane & 7);
                bv[n] = *(const bf16x8*)(bs + row * 64 + c * 8);
            }
#pragma unroll
            for (int m = 0; m < 4; m++)
#pragma unroll
                for (int n = 0; n < 4; n++)
                    acc[m][n] = __builtin_amdgcn_mfma_f32_16x16x32_bf16(
                        af[m], bv[n], acc[m][n], 0, 0, 0);
        }
        __syncthreads();
    }
    // epilogue: C/D layout col=lane&15, row=(lane>>4)*4+j
#pragma unroll
    for (int m = 0; m < 4; m++) {
        int r0 = wm * 64 + m * 16 + (lane >> 4) * 4;
#pragma unroll
        for (int n = 0; n < 4; n++) {
            int col = brow0 + wn * 64 + n * 16 + (lane & 15);
#pragma unroll
            for (int j = 0; j < 4; j++)
                C[(size_t)(arow0 + r0 + j) * 256 + col] = f2bf(acc[m][n][j]);
        }
    }
}

// ---------------- per-node attention logits (one wave per row) ----------------
__launch_bounds__(256)
__global__ void k_natt(const u16* __restrict__ xh, const float* __restrict__ att_s,
                       const float* __restrict__ att_d, float* __restrict__ a_src,
                       float* __restrict__ a_dst) {
    int row  = blockIdx.x * 4 + (threadIdx.x >> 6);
    int lane = threadIdx.x & 63;
    if (row >= N_NODES) return;
    u64 pk = *(const u64*)(xh + (size_t)row * 256 + lane * 4);
    float v0 = bf2f((u16)pk),         v1 = bf2f((u16)(pk >> 16));
    float v2 = bf2f((u16)(pk >> 32)), v3 = bf2f((u16)(pk >> 48));
    float4 s4 = *(const float4*)(att_s + lane * 4);
    float4 d4 = *(const float4*)(att_d + lane * 4);
    float s = v0 * s4.x + v1 * s4.y + v2 * s4.z + v3 * s4.w;
    float d = v0 * d4.x + v1 * d4.y + v2 * d4.z + v3 * d4.w;
#pragma unroll
    for (int m = 4; m >= 1; m >>= 1) {   // reduce within 8-lane head group
        s += __shfl_xor(s, m);
        d += __shfl_xor(d, m);
    }
    if ((lane & 7) == 0) {
        a_src[(size_t)row * 8 + (lane >> 3)] = s;
        a_dst[(size_t)row * 8 + (lane >> 3)] = d;
    }
}

// ---------------- CSR build: histogram(+rank) / scan / scatter ----------------
__global__ void k_hist(const int* __restrict__ ei, int* __restrict__ deg,
                       int* __restrict__ rank) {
    int e = blockIdx.x * 256 + threadIdx.x;
    if (e >= N_EDGES) return;
    rank[e] = atomicAdd(&deg[ei[N_EDGES + e]], 1);
}

__global__ void k_scan1(const int* __restrict__ deg, int* __restrict__ incl,
                        int* __restrict__ bsum) {
    __shared__ int s[256];
    int t = threadIdx.x, idx = blockIdx.x * 256 + t;
    int v = (idx < N_NODES) ? deg[idx] + 1 : 0;   // +1 = self loop slot
    s[t] = v;
    __syncthreads();
    for (int off = 1; off < 256; off <<= 1) {
        int u = (t >= off) ? s[t - off] : 0;
        __syncthreads();
        s[t] += u;
        __syncthreads();
    }
    incl[idx] = s[t];
    if (t == 255) bsum[blockIdx.x] = s[255];
}

__global__ void k_scan2(const int* __restrict__ bsum, int* __restrict__ boff) {
    __shared__ int s[256];
    int t = threadIdx.x;
    int v = (t < NB_SCAN) ? bsum[t] : 0;
    s[t] = v;
    __syncthreads();
    for (int off = 1; off < 256; off <<= 1) {
        int u = (t >= off) ? s[t - off] : 0;
        __syncthreads();
        s[t] += u;
        __syncthreads();
    }
    boff[t] = s[t] - v;   // exclusive
}

__global__ void k_scan3(const int* __restrict__ deg, const int* __restrict__ incl,
                        const int* __restrict__ boff, int* __restrict__ row_start) {
    int idx = blockIdx.x * 256 + threadIdx.x;
    if (idx < N_NODES)
        row_start[idx] = incl[idx] - (deg[idx] + 1) + boff[idx >> 8];
    if (idx == 0) row_start[N_NODES] = N_EDGES + N_NODES;
}

__global__ void k_scatter(const int* __restrict__ ei, const int* __restrict__ rank,
                          const int* __restrict__ row_start, int2* __restrict__ sorted) {
    int e = blockIdx.x * 256 + threadIdx.x;
    if (e >= N_EDGES) return;
    int s = ei[e], d = ei[N_EDGES + e];
    sorted[row_start[d] + rank[e]] = make_int2(s, e);
}

// ---------------- per-node softmax + aggregation ----------------
__launch_bounds__(256)
__global__ void k_node(const u16* __restrict__ xh, const int2* __restrict__ sorted,
                       const int* __restrict__ row_start, const float* __restrict__ a_src,
                       const float* __restrict__ a_dstg, const float* __restrict__ x,
                       const float* __restrict__ bias, float* __restrict__ out,
                       float* __restrict__ alpha) {
    __shared__ float eL[8][EP];                 // [head][k], stride 260: conflict-free
    __shared__ int   sL[MAXE];
    __shared__ int   idL[MAXE];
    __shared__ __align__(16) float partial[4][256];
    __shared__ float adst[8], mh[8], dh[8];
    const int i = blockIdx.x, t = threadIdx.x;
    const int lane = t & 63, w = t >> 6;
    const int start = row_start[i];
    int cnt = row_start[i + 1] - start;         // includes self slot
    if (cnt > MAXE) cnt = MAXE;
    const int degE = cnt - 1;

    if (t < 8) adst[t] = a_dstg[(size_t)i * 8 + t];
    for (int k = t; k < cnt; k += 256) {
        if (k < degE) {
            int2 pr = sorted[start + k];
            sL[k] = pr.x; idL[k] = pr.y;
        } else {
            sL[k] = i;    idL[k] = N_EDGES + i;
        }
    }
    __syncthreads();

    const int tot = cnt * 8;
    for (int idx = t; idx < tot; idx += 256) {
        int k = idx >> 3, h = idx & 7;
        float s = a_src[(size_t)sL[k] * 8 + h] + adst[h];
        eL[h][k] = (s >= 0.f) ? s : SLOPE * s;
    }
    __syncthreads();

    {   // per-head max (head = t>>5, 32 lanes per head)
        int h = t >> 5, c = t & 31;
        float pm = -1e30f;
        for (int k = c; k < cnt; k += 32) pm = fmaxf(pm, eL[h][k]);
#pragma unroll
        for (int m = 16; m >= 1; m >>= 1) pm = fmaxf(pm, __shfl_xor(pm, m));
        if (c == 0) mh[h] = pm;
    }
    __syncthreads();
    {   // exp + per-head sum -> store reciprocal
        int h = t >> 5, c = t & 31;
        float m = mh[h], ps = 0.f;
        for (int k = c; k < cnt; k += 32) {
            float ex = __expf(eL[h][k] - m);
            eL[h][k] = ex;
            ps += ex;
        }
#pragma unroll
        for (int mm = 16; mm >= 1; mm >>= 1) ps += __shfl_xor(ps, mm);
        if (c == 0) dh[h] = 1.0f / (ps + 1e-16f);
    }
    __syncthreads();
    if (t < cnt) {   // alpha: normalize, write back to eL + vector-store to global
        float4 A0, A1;
        A0.x = eL[0][t] * dh[0]; A0.y = eL[1][t] * dh[1];
        A0.z = eL[2][t] * dh[2]; A0.w = eL[3][t] * dh[3];
        A1.x = eL[4][t] * dh[4]; A1.y = eL[5][t] * dh[5];
        A1.z = eL[6][t] * dh[6]; A1.w = eL[7][t] * dh[7];
        eL[0][t] = A0.x; eL[1][t] = A0.y; eL[2][t] = A0.z; eL[3][t] = A0.w;
        eL[4][t] = A1.x; eL[5][t] = A1.y; eL[6][t] = A1.z; eL[7][t] = A1.w;
        float4* ap = (float4*)(alpha + (size_t)idL[t] * 8);
        ap[0] = A0; ap[1] = A1;
    }
    __syncthreads();
    {   // aggregation: wave w handles k = w, w+4, ...; lane covers 4 channels (u64)
        const int h = lane >> 3;
        f32x4 acc = {0.f, 0.f, 0.f, 0.f};
        for (int k = w; k < cnt; k += 4) {
            float al = eL[h][k];
            u64 pk = *(const u64*)(xh + (size_t)sL[k] * 256 + lane * 4);
            acc[0] += al * bf2f((u16)pk);
            acc[1] += al * bf2f((u16)(pk >> 16));
            acc[2] += al * bf2f((u16)(pk >> 32));
            acc[3] += al * bf2f((u16)(pk >> 48));
        }
        *(f32x4*)&partial[w][lane * 4] = acc;
    }
    __syncthreads();
    {
        float s = partial[0][t] + partial[1][t] + partial[2][t] + partial[3][t];
        out[(size_t)i * 256 + t] = s + bias[t] + x[(size_t)i * 256 + t];
    }
}

extern "C" void kernel_launch(void* const* d_in, const int* in_sizes, int n_in,
                              void* d_out, int out_size, void* d_ws, size_t ws_size,
                              hipStream_t stream) {
    const float* x     = (const float*)d_in[0];
    const int*   ei    = (const int*)d_in[1];    // (2,E) int32
    const float* W     = (const float*)d_in[2];
    const float* att_s = (const float*)d_in[3];
    const float* att_d = (const float*)d_in[4];
    const float* bias  = (const float*)d_in[5];
    float* out   = (float*)d_out;
    float* alpha = out + (size_t)N_NODES * HC;

    char* p = (char*)d_ws;
    u16* xb = (u16*)p;        p += (size_t)MPAD * 256 * 2;
    u16* xh = (u16*)p;        p += (size_t)MPAD * 256 * 2;
    u16* Wt = (u16*)p;        p += 256 * 256 * 2;
    float* a_src = (float*)p; p += (size_t)N_NODES * 8 * 4;
    float* a_dst = (float*)p; p += (size_t)N_NODES * 8 * 4;
    int* deg  = (int*)p;      p += (size_t)N_NODES * 4;
    int* incl = (int*)p;      p += (size_t)NB_SCAN * 256 * 4;
    int* bsum = (int*)p;      p += 256 * 4;
    int* boff = (int*)p;      p += 256 * 4;
    int* row_start = (int*)p; p += ((size_t)(N_NODES + 1) * 4 + 15) / 16 * 16;
    int2* sorted = (int2*)p;  p += (size_t)(N_EDGES + N_NODES) * 8;  // fix: incl self slots
    int* rank = (int*)xb;     // alias: xb dead after k_gemm, rank written after

    hipMemsetAsync(deg, 0, (size_t)N_NODES * 4, stream);
    k_conv_x<<<MPAD * 256 / 8 / 256, 256, 0, stream>>>(x, xb);
    k_conv_w<<<256, 256, 0, stream>>>(W, Wt);
    dim3 gg(MPAD / 128, 2);
    k_gemm<<<gg, 256, 0, stream>>>(xb, Wt, xh);
    k_natt<<<(N_NODES + 3) / 4, 256, 0, stream>>>(xh, att_s, att_d, a_src, a_dst);
    k_hist<<<(N_EDGES + 255) / 256, 256, 0, stream>>>(ei, deg, rank);
    k_scan1<<<NB_SCAN, 256, 0, stream>>>(deg, incl, bsum);
    k_scan2<<<1, 256, 0, stream>>>(bsum, boff);
    k_scan3<<<NB_SCAN, 256, 0, stream>>>(deg, incl, boff, row_start);
    k_scatter<<<(N_EDGES + 255) / 256, 256, 0, stream>>>(ei, rank, row_start, sorted);
    k_node<<<N_NODES, 256, 0, stream>>>(xh, sorted, row_start, a_src, a_dst, x, bias,
                                        out, alpha);
}

// Round 4
// 300.384 us; speedup vs baseline: 1.3301x; 1.1188x over previous
//
#include <hip/hip_runtime.h>
#include <stdint.h>

// ---------------- problem constants ----------------
#define N_NODES 50000
#define N_EDGES 800000
#define IN_CH   256
#define HC      256      // HEADS * CPH
#define HEADS   8
#define SLOPE   0.2f
#define MPAD    50048    // 391 * 128 (GEMM row padding)
#define NB_SCAN 196      // ceil(50000/256)
#define MAXD    256      // max in-degree capacity (Binomial(800K,1/50K)~Poisson(16))

typedef __attribute__((ext_vector_type(8))) short bf16x8;
typedef __attribute__((ext_vector_type(4))) float f32x4;
typedef unsigned short u16;
typedef unsigned int   u32;
typedef unsigned long long u64;
typedef __attribute__((ext_vector_type(2))) u64 u64x2;

static __device__ __forceinline__ float bf2f(u16 u) {
    return __uint_as_float(((u32)u) << 16);
}
static __device__ __forceinline__ u16 f2bf(float f) {
    u32 b = __float_as_uint(f);
    b += 0x7fffu + ((b >> 16) & 1u);   // RNE (finite values)
    return (u16)(b >> 16);
}

// async global->LDS, 16B per lane. LDS dest = wave-uniform base + lane*16.
#define ASYNC16(g, l) __builtin_amdgcn_global_load_lds(                      \
    (const __attribute__((address_space(1))) u32*)(uintptr_t)(g),            \
    (__attribute__((address_space(3))) u32*)(uintptr_t)(l), 16, 0, 0)

// ---------------- fused prep: x->bf16 | W transpose->bf16 | degree hist ----------------
#define NB_CONVX (MPAD / 8)          // 6256 blocks, 8 elem/thread
#define NB_W     256
#define NB_HIST  ((N_EDGES + 255) / 256)

__global__ void k_prep(const float* __restrict__ x, u16* __restrict__ xb,
                       const float* __restrict__ W, u16* __restrict__ Wt,
                       const int* __restrict__ ei, int* __restrict__ deg,
                       int* __restrict__ rank) {
    int bid = blockIdx.x, t = threadIdx.x;
    if (bid < NB_CONVX) {
        size_t base = ((size_t)bid * 256 + t) * 8;
        int row = (int)(base >> 8);
        float4 v0 = make_float4(0.f, 0.f, 0.f, 0.f), v1 = v0;
        if (row < N_NODES) {
            v0 = *(const float4*)(x + base);
            v1 = *(const float4*)(x + base + 4);
        }
        u64 lo = (u64)f2bf(v0.x) | ((u64)f2bf(v0.y) << 16) |
                 ((u64)f2bf(v0.z) << 32) | ((u64)f2bf(v0.w) << 48);
        u64 hi = (u64)f2bf(v1.x) | ((u64)f2bf(v1.y) << 16) |
                 ((u64)f2bf(v1.z) << 32) | ((u64)f2bf(v1.w) << 48);
        *(u64*)(xb + base)     = lo;
        *(u64*)(xb + base + 4) = hi;
    } else if (bid < NB_CONVX + NB_W) {
        int hc = bid - NB_CONVX;
        Wt[hc * 256 + t] = f2bf(W[t * 256 + hc]);
    } else {
        int e = (bid - NB_CONVX - NB_W) * 256 + t;
        if (e < N_EDGES) rank[e] = atomicAdd(&deg[ei[N_EDGES + e]], 1);
    }
}

// ---------------- bf16 MFMA GEMM: xh = x @ W  (MPADx256 * 256x256) ----------------
__device__ __forceinline__ void stage_tile(const u16* __restrict__ A,
                                           const u16* __restrict__ B,
                                           u16* as, u16* bs, int arow0, int brow0,
                                           int kt, int w, int rr, int ch) {
    int sch = ch ^ (rr & 7);   // source chunk swizzle (involution)
#pragma unroll
    for (int ii = 0; ii < 4; ii++) {
        int rq = w * 32 + ii * 8;
        ASYNC16(A + (size_t)(arow0 + rq + rr) * 256 + kt * 64 + sch * 8, as + rq * 64);
        ASYNC16(B + (size_t)(brow0 + rq + rr) * 256 + kt * 64 + sch * 8, bs + rq * 64);
    }
}

__launch_bounds__(256)
__global__ void k_gemm(const u16* __restrict__ A, const u16* __restrict__ B,
                       u16* __restrict__ C) {
    __shared__ u16 As[2][128 * 64];
    __shared__ u16 Bs[2][128 * 64];
    const int tid  = threadIdx.x;
    const int lane = tid & 63;
    const int w    = tid >> 6;
    const int wm   = w >> 1, wn = w & 1;
    const int arow0 = blockIdx.x * 128;
    const int brow0 = blockIdx.y * 128;
    const int rr = lane >> 3, ch = lane & 7;

    f32x4 acc[4][4];
#pragma unroll
    for (int m = 0; m < 4; m++)
#pragma unroll
        for (int n = 0; n < 4; n++) acc[m][n] = (f32x4){0.f, 0.f, 0.f, 0.f};

    stage_tile(A, B, As[0], Bs[0], arow0, brow0, 0, w, rr, ch);
    __syncthreads();

    for (int kt = 0; kt < 4; ++kt) {
        int cur = kt & 1;
        if (kt < 3)
            stage_tile(A, B, As[cur ^ 1], Bs[cur ^ 1], arow0, brow0, kt + 1, w, rr, ch);
        const u16* as = As[cur];
        const u16* bs = Bs[cur];
#pragma unroll
        for (int kk = 0; kk < 2; kk++) {
            bf16x8 af[4], bv[4];
#pragma unroll
            for (int m = 0; m < 4; m++) {
                int row = wm * 64 + m * 16 + (lane & 15);
                int c   = (kk * 4 + (lane >> 4)) ^ (lane & 7);
                af[m] = *(const bf16x8*)(as + row * 64 + c * 8);
            }
#pragma unroll
            for (int n = 0; n < 4; n++) {
                int row = wn * 64 + n * 16 + (lane & 15);
                int c   = (kk * 4 + (lane >> 4)) ^ (lane & 7);
                bv[n] = *(const bf16x8*)(bs + row * 64 + c * 8);
            }
#pragma unroll
            for (int m = 0; m < 4; m++)
#pragma unroll
                for (int n = 0; n < 4; n++)
                    acc[m][n] = __builtin_amdgcn_mfma_f32_16x16x32_bf16(
                        af[m], bv[n], acc[m][n], 0, 0, 0);
        }
        __syncthreads();
    }
#pragma unroll
    for (int m = 0; m < 4; m++) {
        int r0 = wm * 64 + m * 16 + (lane >> 4) * 4;
#pragma unroll
        for (int n = 0; n < 4; n++) {
            int col = brow0 + wn * 64 + n * 16 + (lane & 15);
#pragma unroll
            for (int j = 0; j < 4; j++)
                C[(size_t)(arow0 + r0 + j) * 256 + col] = f2bf(acc[m][n][j]);
        }
    }
}

// ---------------- per-node attention logits (one wave per row) ----------------
__launch_bounds__(256)
__global__ void k_natt(const u16* __restrict__ xh, const float* __restrict__ att_s,
                       const float* __restrict__ att_d, float* __restrict__ a_src,
                       float* __restrict__ a_dst) {
    int row  = blockIdx.x * 4 + (threadIdx.x >> 6);
    int lane = threadIdx.x & 63;
    if (row >= N_NODES) return;
    u64 pk = *(const u64*)(xh + (size_t)row * 256 + lane * 4);
    float v0 = bf2f((u16)pk),         v1 = bf2f((u16)(pk >> 16));
    float v2 = bf2f((u16)(pk >> 32)), v3 = bf2f((u16)(pk >> 48));
    float4 s4 = *(const float4*)(att_s + lane * 4);
    float4 d4 = *(const float4*)(att_d + lane * 4);
    float s = v0 * s4.x + v1 * s4.y + v2 * s4.z + v3 * s4.w;
    float d = v0 * d4.x + v1 * d4.y + v2 * d4.z + v3 * d4.w;
#pragma unroll
    for (int m = 4; m >= 1; m >>= 1) {
        s += __shfl_xor(s, m);
        d += __shfl_xor(d, m);
    }
    if ((lane & 7) == 0) {
        a_src[(size_t)row * 8 + (lane >> 3)] = s;
        a_dst[(size_t)row * 8 + (lane >> 3)] = d;
    }
}

// ---------------- scans + scatter ----------------
__global__ void k_scan1(const int* __restrict__ deg, int* __restrict__ incl,
                        int* __restrict__ bsum) {
    __shared__ int s[256];
    int t = threadIdx.x, idx = blockIdx.x * 256 + t;
    int v = (idx < N_NODES) ? deg[idx] + 1 : 0;   // +1 = self loop slot
    s[t] = v;
    __syncthreads();
    for (int off = 1; off < 256; off <<= 1) {
        int u = (t >= off) ? s[t - off] : 0;
        __syncthreads();
        s[t] += u;
        __syncthreads();
    }
    incl[idx] = s[t];
    if (t == 255) bsum[blockIdx.x] = s[255];
}

__global__ void k_scan2(const int* __restrict__ bsum, int* __restrict__ boff) {
    __shared__ int s[256];
    int t = threadIdx.x;
    int v = (t < NB_SCAN) ? bsum[t] : 0;
    s[t] = v;
    __syncthreads();
    for (int off = 1; off < 256; off <<= 1) {
        int u = (t >= off) ? s[t - off] : 0;
        __syncthreads();
        s[t] += u;
        __syncthreads();
    }
    boff[t] = s[t] - v;   // exclusive
}

__global__ void k_scan3(const int* __restrict__ deg, const int* __restrict__ incl,
                        const int* __restrict__ boff, int* __restrict__ row_start) {
    int idx = blockIdx.x * 256 + threadIdx.x;
    if (idx < N_NODES)
        row_start[idx] = incl[idx] - (deg[idx] + 1) + boff[idx >> 8];
    if (idx == 0) row_start[N_NODES] = N_EDGES + N_NODES;
}

__global__ void k_scatter(const int* __restrict__ ei, const int* __restrict__ rank,
                          const int* __restrict__ row_start, int2* __restrict__ sorted) {
    int e = blockIdx.x * 256 + threadIdx.x;
    if (e >= N_EDGES) return;
    int s = ei[e], d = ei[N_EDGES + e];
    sorted[row_start[d] + rank[e]] = make_int2(s, e);
}

// ---------------- per-node softmax + aggregation: ONE WAVE PER NODE ----------------
__launch_bounds__(256)
__global__ void k_node(const u16* __restrict__ xh, const int2* __restrict__ sorted,
                       const int* __restrict__ row_start, const float* __restrict__ a_src,
                       const float* __restrict__ a_dstg, const float* __restrict__ x,
                       const float* __restrict__ bias, float* __restrict__ out,
                       float* __restrict__ alpha) {
    __shared__ int sLs[4][MAXD];
    __shared__ int idLs[4][MAXD];
    const int w = threadIdx.x >> 6, lane = threadIdx.x & 63;
    const int i = blockIdx.x * 4 + w;               // grid = 12500 -> exact
    int* sL  = sLs[w];
    int* idL = idLs[w];

    const int start = row_start[i];
    int cnt = row_start[i + 1] - start;             // includes self slot
    if (cnt > MAXD) cnt = MAXD;
    const int degE = cnt - 1;

    // fill edge list (own-wave LDS)
    for (int k = lane; k < cnt; k += 64) {
        int2 pr;
        if (k < degE) pr = sorted[start + k];
        else { pr.x = i; pr.y = N_EDGES + i; }
        sL[k]  = pr.x;
        idL[k] = pr.y;
    }
    __syncthreads();   // cross-lane LDS visibility (single cheap barrier)

    const int h = lane & 7;                          // head for passes 1-3
    const float adst = a_dstg[(size_t)i * 8 + h];
    const int tot = cnt * 8;

    // pass 1: per-head max  (idx = (k<<3)|h; stride 64 keeps h fixed)
    float pm = -1e30f;
    for (int idx = lane; idx < tot; idx += 64) {
        int k = idx >> 3;
        float s = a_src[(size_t)sL[k] * 8 + h] + adst;
        s = (s >= 0.f) ? s : SLOPE * s;
        pm = fmaxf(pm, s);
    }
    pm = fmaxf(pm, __shfl_xor(pm, 8));
    pm = fmaxf(pm, __shfl_xor(pm, 16));
    pm = fmaxf(pm, __shfl_xor(pm, 32));

    // pass 2: per-head sum (a_src now cache-hot)
    float ps = 0.f;
    for (int idx = lane; idx < tot; idx += 64) {
        int k = idx >> 3;
        float s = a_src[(size_t)sL[k] * 8 + h] + adst;
        s = (s >= 0.f) ? s : SLOPE * s;
        ps += __expf(s - pm);
    }
    ps += __shfl_xor(ps, 8);
    ps += __shfl_xor(ps, 16);
    ps += __shfl_xor(ps, 32);
    const float rinv = 1.0f / (ps + 1e-16f);

    // pass 3: alpha write (recompute)
    for (int idx = lane; idx < tot; idx += 64) {
        int k = idx >> 3;
        float s = a_src[(size_t)sL[k] * 8 + h] + adst;
        s = (s >= 0.f) ? s : SLOPE * s;
        alpha[(size_t)idL[k] * 8 + h] = __expf(s - pm) * rinv;
    }

    // pass 4: aggregation. 4 lane-groups of 16 each take k = g, g+4, ...
    // lane covers 16 channels [l16*16, l16*16+16) -> single head h4 = l16>>1.
    const int g = lane >> 4, l16 = lane & 15;
    const int h4 = l16 >> 1;
    const float m4    = __shfl(pm, h4);
    const float rinv4 = __shfl(rinv, h4);
    const float adst4 = __shfl(adst, h4);
    float acc[16];
#pragma unroll
    for (int j = 0; j < 16; j++) acc[j] = 0.f;

    for (int k = g; k < cnt; k += 4) {
        int sl = sL[k];
        float s = a_src[(size_t)sl * 8 + h4] + adst4;     // broadcast in 16-group
        s = (s >= 0.f) ? s : SLOPE * s;
        float al = __expf(s - m4) * rinv4;
        const u16* xr = xh + (size_t)sl * 256 + l16 * 16;
        u64x2 q0 = *(const u64x2*)(xr);
        u64x2 q1 = *(const u64x2*)(xr + 8);
#pragma unroll
        for (int j = 0; j < 4; j++) acc[j]      += al * bf2f((u16)(q0.x >> (16 * j)));
#pragma unroll
        for (int j = 0; j < 4; j++) acc[4 + j]  += al * bf2f((u16)(q0.y >> (16 * j)));
#pragma unroll
        for (int j = 0; j < 4; j++) acc[8 + j]  += al * bf2f((u16)(q1.x >> (16 * j)));
#pragma unroll
        for (int j = 0; j < 4; j++) acc[12 + j] += al * bf2f((u16)(q1.y >> (16 * j)));
    }
    // cross-group reduce (groups differ in lane bits 4-5)
#pragma unroll
    for (int j = 0; j < 16; j++) {
        acc[j] += __shfl_xor(acc[j], 16);
        acc[j] += __shfl_xor(acc[j], 32);
    }
    // epilogue: lanes 0-15 write their 16 channels (+bias +residual)
    if (lane < 16) {
        const size_t o = (size_t)i * 256 + l16 * 16;
#pragma unroll
        for (int q = 0; q < 4; q++) {
            float4 xv = *(const float4*)(x + o + q * 4);
            float4 bv = *(const float4*)(bias + l16 * 16 + q * 4);
            float4 ov;
            ov.x = acc[q * 4 + 0] + xv.x + bv.x;
            ov.y = acc[q * 4 + 1] + xv.y + bv.y;
            ov.z = acc[q * 4 + 2] + xv.z + bv.z;
            ov.w = acc[q * 4 + 3] + xv.w + bv.w;
            *(float4*)(out + o + q * 4) = ov;
        }
    }
}

extern "C" void kernel_launch(void* const* d_in, const int* in_sizes, int n_in,
                              void* d_out, int out_size, void* d_ws, size_t ws_size,
                              hipStream_t stream) {
    const float* x     = (const float*)d_in[0];
    const int*   ei    = (const int*)d_in[1];    // (2,E) int32
    const float* W     = (const float*)d_in[2];
    const float* att_s = (const float*)d_in[3];
    const float* att_d = (const float*)d_in[4];
    const float* bias  = (const float*)d_in[5];
    float* out   = (float*)d_out;
    float* alpha = out + (size_t)N_NODES * HC;

    char* p = (char*)d_ws;
    u16* xb = (u16*)p;        p += (size_t)MPAD * 256 * 2;
    u16* xh = (u16*)p;        p += (size_t)MPAD * 256 * 2;
    u16* Wt = (u16*)p;        p += 256 * 256 * 2;
    float* a_src = (float*)p; p += (size_t)N_NODES * 8 * 4;
    float* a_dst = (float*)p; p += (size_t)N_NODES * 8 * 4;
    int* deg  = (int*)p;      p += (size_t)N_NODES * 4;
    int* incl = (int*)p;      p += (size_t)NB_SCAN * 256 * 4;
    int* bsum = (int*)p;      p += 256 * 4;
    int* boff = (int*)p;      p += 256 * 4;
    int* row_start = (int*)p; p += ((size_t)(N_NODES + 1) * 4 + 15) / 16 * 16;
    int* rank = (int*)p;      p += (size_t)N_EDGES * 4;          // own region now
    int2* sorted = (int2*)p;  p += (size_t)(N_EDGES + N_NODES) * 8;

    hipMemsetAsync(deg, 0, (size_t)N_NODES * 4, stream);
    k_prep<<<NB_CONVX + NB_W + NB_HIST, 256, 0, stream>>>(x, xb, W, Wt, ei, deg, rank);
    dim3 gg(MPAD / 128, 2);
    k_gemm<<<gg, 256, 0, stream>>>(xb, Wt, xh);
    k_natt<<<(N_NODES + 3) / 4, 256, 0, stream>>>(xh, att_s, att_d, a_src, a_dst);
    k_scan1<<<NB_SCAN, 256, 0, stream>>>(deg, incl, bsum);
    k_scan2<<<1, 256, 0, stream>>>(bsum, boff);
    k_scan3<<<NB_SCAN, 256, 0, stream>>>(deg, incl, boff, row_start);
    k_scatter<<<(N_EDGES + 255) / 256, 256, 0, stream>>>(ei, rank, row_start, sorted);
    k_node<<<N_NODES / 4, 256, 0, stream>>>(xh, sorted, row_start, a_src, a_dst, x, bias,
                                            out, alpha);
}